// Round 1
// 4696.660 us; speedup vs baseline: 2.3214x; 2.3214x over previous
//
#include <hip/hip_runtime.h>
#include <hip/hip_bf16.h>
#include <cmath>

typedef __attribute__((ext_vector_type(8))) short short8;   // 8 bf16 = 4 VGPRs
typedef __attribute__((ext_vector_type(4))) float floatx4;  // MFMA 16x16 accumulator

#define NB   64
#define TS   512
#define DIM  1024
#define HD   1024
#define KTOT 2048
#define GRID_BLOCKS 256
#define BSTRIDE 2056                  // Bt row stride (bf16 elems): 4112B -> 2-way bank alias (free)
#define ROWSTRIDE ((size_t)TS * HD)   // batch-row stride of x and out (elements)

// ---------------------------------------------------------------------------
// One-time transpose + fp32->bf16: WT[j][k] = bf16( k<1024 ? Wx[k][j] : Wh[k-1024][j] )
// ---------------------------------------------------------------------------
__global__ void build_wt(const float* __restrict__ Wx,
                         const float* __restrict__ Wh,
                         __hip_bfloat16* __restrict__ WT) {
    __shared__ __hip_bfloat16 tile[32][33];
    const int j0 = blockIdx.x * 32;
    const int k0 = blockIdx.y * 32;
    const int tx = threadIdx.x & 31;
    const int ty = threadIdx.x >> 5;
    #pragma unroll
    for (int kk = 0; kk < 32; kk += 8) {
        const int k = k0 + ty + kk;
        const float* S = (k < DIM) ? (Wx + (size_t)k * 4096)
                                   : (Wh + (size_t)(k - DIM) * 4096);
        tile[ty + kk][tx] = __float2bfloat16(S[j0 + tx]);
    }
    __syncthreads();
    #pragma unroll
    for (int kk = 0; kk < 32; kk += 8) {
        const int j = j0 + ty + kk;
        WT[(size_t)j * KTOT + k0 + tx] = tile[tx][ty + kk];
    }
}

// ---------------------------------------------------------------------------
// Persistent LSTM scan — fence-free cross-XCD h exchange.
//
// Coherence scheme: hbuf is only ever touched through agent-scope RELAXED
// atomics (compile to global_load/store with sc0 sc1 -> read/write-through at
// the LLC). Flags are agent-scope atomics as before. Release ordering for the
// flag is provided by __syncthreads(): the compiler emits
// s_waitcnt vmcnt(0) before s_barrier, so every wave's write-through h stores
// are LLC-acked before tid0 issues the flag store. No buffer_wbl2 / buffer_inv
// per step -> x and WT stay warm in per-XCD L2.
//
// Barrier scope: block (ng,cs) only exchanges h with blocks (ng,*), so the
// grid barrier is split into 4 independent 64-block group barriers.
// ng = (blk%8)>>1 places each group on one XCD pair under round-robin
// dispatch (performance heuristic only; correctness does not depend on it).
// ---------------------------------------------------------------------------
__global__ __launch_bounds__(256, 1)
void lstm_scan(const float* __restrict__ x,
               const float* __restrict__ h0,
               const __hip_bfloat16* __restrict__ WT,
               const float* __restrict__ bias,
               float* __restrict__ out,
               __hip_bfloat16* __restrict__ hbuf,   // 2 * 64*1024 bf16
               unsigned* __restrict__ flags) {
    __shared__ __hip_bfloat16 Bt[16][BSTRIDE];  // [n][k]: k<1024 x, k>=1024 h
    __shared__ float lds_g[4][16][17];          // [gate][j_local][n_local]

    const int blk  = blockIdx.x;
    const int ng   = (blk >> 1) & 3;                    // XCD-pair group
    const int cs   = ((blk >> 3) << 1) | (blk & 1);     // 0..63 within group
    const int tid  = threadIdx.x;
    const int wave = tid >> 6;
    const int lane = tid & 63;
    const int n0 = ng * 16;
    const int j0 = cs * 16;
    unsigned* const gflag = flags + ng * 64;            // this group's 64 flags

    const int frag_m = lane & 15;        // A: m (gate-col) / B: n (batch row)
    const int frag_k = (lane >> 4) * 8;  // k sub-offset within 32-chunk

    // ---- preload this wave's A fragments: 64 x short8 = 256 regs ----
    const __hip_bfloat16* wrow =
        WT + (size_t)(wave * HD + j0 + frag_m) * KTOT + frag_k;
    short8 wreg[64];
    #pragma unroll
    for (int i = 0; i < 32; ++i)
        wreg[i] = *(const short8*)(wrow + i * 32);
    #pragma unroll
    for (int i = 0; i < 32; ++i)
        wreg[32 + i] = *(const short8*)(wrow + DIM + i * 32);

    // ---- init: h0 -> hbuf[parity 0] (write-through, agent scope) ----
    const int flat = blk * 256 + tid;    // 0..65535
    __hip_atomic_store((unsigned short*)(hbuf + flat),
                       (unsigned short)__bfloat16_as_short(__float2bfloat16(h0[flat])),
                       __ATOMIC_RELAXED, __HIP_MEMORY_SCOPE_AGENT);

    __syncthreads();   // drains vmcnt for all waves -> h0 stores visible at LLC
    if (tid == 0)
        __hip_atomic_store(gflag + cs, 1u,
                           __ATOMIC_RELAXED, __HIP_MEMORY_SCOPE_AGENT);

    // ---- stage x_0 into Bt x-half (overlaps peers' init) ----
    {
        #pragma unroll
        for (int j = 0; j < 8; ++j) {
            const int c = j * 256 + tid;        // 16B chunk id, 0..2047
            const int r = c >> 7;               // row 0..15
            const int col = (c & 127) * 8;      // 0..1016
            const float* xs = x + (size_t)(n0 + r) * ROWSTRIDE + col;
            float4 f0 = *(const float4*)xs;
            float4 f1 = *(const float4*)(xs + 4);
            short8 v;
            v[0] = __bfloat16_as_short(__float2bfloat16(f0.x));
            v[1] = __bfloat16_as_short(__float2bfloat16(f0.y));
            v[2] = __bfloat16_as_short(__float2bfloat16(f0.z));
            v[3] = __bfloat16_as_short(__float2bfloat16(f0.w));
            v[4] = __bfloat16_as_short(__float2bfloat16(f1.x));
            v[5] = __bfloat16_as_short(__float2bfloat16(f1.y));
            v[6] = __bfloat16_as_short(__float2bfloat16(f1.z));
            v[7] = __bfloat16_as_short(__float2bfloat16(f1.w));
            *(short8*)&Bt[r][col] = v;
        }
    }

    // ---- wait peers' h0 (all waves poll; no intra-block sync needed) ----
    for (;;) {
        unsigned v = __hip_atomic_load(gflag + lane,
                                       __ATOMIC_RELAXED, __HIP_MEMORY_SCOPE_AGENT);
        if (__all((int)(v >= 1u))) break;
        __builtin_amdgcn_s_sleep(1);
    }

    // ---- epilogue mapping ----
    const int e_j = tid & 15;
    const int e_n = tid >> 4;
    float c_reg = 0.0f;
    const float bi  = bias[         j0 + e_j];
    const float bf_ = bias[1 * HD + j0 + e_j];
    const float bo  = bias[2 * HD + j0 + e_j];
    const float bg  = bias[3 * HD + j0 + e_j];
    float* out_e = out + (size_t)(n0 + e_n) * ROWSTRIDE + j0 + e_j;
    const int hb_idx = (n0 + e_n) * 1024 + j0 + e_j;
    const int q = lane >> 4;

    for (int t = 0; t < TS; ++t) {
        const int par = (t & 1) * 65536;

        // ---- stage h_{t-1} into Bt h-half (read-through 8B loads) ----
        #pragma unroll
        for (int j = 0; j < 8; ++j) {
            const int c = j * 256 + tid;
            const int r = c >> 7;
            const int col = (c & 127) * 8;
            const unsigned long long* hp =
                (const unsigned long long*)(hbuf + par + (n0 + r) * 1024 + col);
            unsigned long long lo = __hip_atomic_load(hp,
                __ATOMIC_RELAXED, __HIP_MEMORY_SCOPE_AGENT);
            unsigned long long hi = __hip_atomic_load(hp + 1,
                __ATOMIC_RELAXED, __HIP_MEMORY_SCOPE_AGENT);
            unsigned long long* dst = (unsigned long long*)&Bt[r][1024 + col];
            dst[0] = lo;
            dst[1] = hi;
        }
        __syncthreads();   // S1: all staging (x-half from prev iter + h-half) visible

        // ---- MFMA: A from regs, B from LDS ----
        floatx4 acc = {0.f, 0.f, 0.f, 0.f};
        #pragma unroll
        for (int i = 0; i < 32; ++i) {
            short8 b8 = *(const short8*)&Bt[frag_m][i * 32 + frag_k];
            acc = __builtin_amdgcn_mfma_f32_16x16x32_bf16(wreg[i], b8, acc, 0, 0, 0);
        }
        #pragma unroll
        for (int i = 0; i < 32; ++i) {
            short8 b8 = *(const short8*)&Bt[frag_m][1024 + i * 32 + frag_k];
            acc = __builtin_amdgcn_mfma_f32_16x16x32_bf16(wreg[32 + i], b8, acc, 0, 0, 0);
        }

        // ---- gate tile -> lds_g ----
        #pragma unroll
        for (int r = 0; r < 4; ++r)
            lds_g[wave][q * 4 + r][frag_m] = acc[r];
        __syncthreads();   // S2

        // ---- gates + state update ----
        const float ai = lds_g[0][e_j][e_n] + bi;
        const float af = lds_g[1][e_j][e_n] + bf_;
        const float ao = lds_g[2][e_j][e_n] + bo;
        const float ag = lds_g[3][e_j][e_n] + bg;
        const float i_g = 1.0f / (1.0f + expf(-ai));
        const float f_g = 1.0f / (1.0f + expf(-af));
        const float o_g = 1.0f / (1.0f + expf(-ao));
        const float g_g = tanhf(ag);
        c_reg = f_g * c_reg + i_g * g_g;
        const float h = o_g * tanhf(c_reg);

        // ---- publish h (write-through), then signal ----
        const int npar = ((t + 1) & 1) * 65536;
        __hip_atomic_store((unsigned short*)(hbuf + npar + hb_idx),
                           (unsigned short)__bfloat16_as_short(__float2bfloat16(h)),
                           __ATOMIC_RELAXED, __HIP_MEMORY_SCOPE_AGENT);
        __syncthreads();   // S3: drains vmcnt for all waves -> h at LLC
        if (tid == 0)
            __hip_atomic_store(gflag + cs, (unsigned)(t + 2),
                               __ATOMIC_RELAXED, __HIP_MEMORY_SCOPE_AGENT);

        // fp32 output store — off the critical path, flushed at kernel end
        out_e[(size_t)t * HD] = h;

        if (t + 1 < TS) {
            // ---- stage x_{t+1} into Bt x-half (overlaps peers' arrival) ----
            #pragma unroll
            for (int j = 0; j < 8; ++j) {
                const int c = j * 256 + tid;
                const int r = c >> 7;
                const int col = (c & 127) * 8;
                const float* xs = x + (size_t)(n0 + r) * ROWSTRIDE
                                    + (size_t)(t + 1) * DIM + col;
                float4 f0 = *(const float4*)xs;
                float4 f1 = *(const float4*)(xs + 4);
                short8 v;
                v[0] = __bfloat16_as_short(__float2bfloat16(f0.x));
                v[1] = __bfloat16_as_short(__float2bfloat16(f0.y));
                v[2] = __bfloat16_as_short(__float2bfloat16(f0.z));
                v[3] = __bfloat16_as_short(__float2bfloat16(f0.w));
                v[4] = __bfloat16_as_short(__float2bfloat16(f1.x));
                v[5] = __bfloat16_as_short(__float2bfloat16(f1.y));
                v[6] = __bfloat16_as_short(__float2bfloat16(f1.z));
                v[7] = __bfloat16_as_short(__float2bfloat16(f1.w));
                *(short8*)&Bt[r][col] = v;
            }

            // ---- group barrier: poll this group's 64 flags (all waves) ----
            const unsigned tgt = (unsigned)(t + 2);
            for (;;) {
                unsigned v = __hip_atomic_load(gflag + lane,
                    __ATOMIC_RELAXED, __HIP_MEMORY_SCOPE_AGENT);
                if (__all((int)(v >= tgt))) break;
                __builtin_amdgcn_s_sleep(1);
            }
        }
    }
}

// ---------------------------------------------------------------------------
extern "C" void kernel_launch(void* const* d_in, const int* in_sizes, int n_in,
                              void* d_out, int out_size, void* d_ws, size_t ws_size,
                              hipStream_t stream) {
    const float* x  = (const float*)d_in[0];
    const float* h0 = (const float*)d_in[1];
    const float* Wx = (const float*)d_in[2];
    const float* Wh = (const float*)d_in[3];
    const float* b  = (const float*)d_in[4];
    float* out = (float*)d_out;

    char* ws = (char*)d_ws;
    __hip_bfloat16* WT    = (__hip_bfloat16*)ws;                         // 16 MiB
    unsigned*       flags = (unsigned*)(ws + (16u << 20));               // 1 KiB (4K pad)
    __hip_bfloat16* hbuf  = (__hip_bfloat16*)(ws + (16u << 20) + 4096);  // 256 KiB

    hipMemsetAsync(flags, 0, 4096, stream);
    build_wt<<<dim3(128, 64), 256, 0, stream>>>(Wx, Wh, WT);
    lstm_scan<<<GRID_BLOCKS, 256, 0, stream>>>(x, h0, WT, b, out, hbuf, flags);
}

// Round 2
// 4483.260 us; speedup vs baseline: 2.4319x; 1.0476x over previous
//
#include <hip/hip_runtime.h>
#include <hip/hip_bf16.h>
#include <cmath>

typedef __attribute__((ext_vector_type(8))) short short8;   // 8 bf16 = 4 VGPRs
typedef __attribute__((ext_vector_type(4))) float floatx4;  // MFMA 16x16 accumulator

#define NB   64
#define TS   512
#define DIM  1024
#define HD   1024
#define KTOT 2048
#define GRID_BLOCKS 256
#define BSTRIDE 2056                  // Bt row stride (bf16 elems): 4112B -> 2-way bank alias (free)
#define ROWSTRIDE ((size_t)TS * HD)   // batch-row stride of x and out (elements)
#define FSTRIDE 16                    // flag spread: 16 dwords = 64B = 1 cache line per flag

// ---------------------------------------------------------------------------
// One-time transpose + fp32->bf16: WT[j][k] = bf16( k<1024 ? Wx[k][j] : Wh[k-1024][j] )
// ---------------------------------------------------------------------------
__global__ void build_wt(const float* __restrict__ Wx,
                         const float* __restrict__ Wh,
                         __hip_bfloat16* __restrict__ WT) {
    __shared__ __hip_bfloat16 tile[32][33];
    const int j0 = blockIdx.x * 32;
    const int k0 = blockIdx.y * 32;
    const int tx = threadIdx.x & 31;
    const int ty = threadIdx.x >> 5;
    #pragma unroll
    for (int kk = 0; kk < 32; kk += 8) {
        const int k = k0 + ty + kk;
        const float* S = (k < DIM) ? (Wx + (size_t)k * 4096)
                                   : (Wh + (size_t)(k - DIM) * 4096);
        tile[ty + kk][tx] = __float2bfloat16(S[j0 + tx]);
    }
    __syncthreads();
    #pragma unroll
    for (int kk = 0; kk < 32; kk += 8) {
        const int j = j0 + ty + kk;
        WT[(size_t)j * KTOT + k0 + tx] = tile[tx][ty + kk];
    }
}

// ---------------------------------------------------------------------------
// Persistent LSTM scan — fence-free cross-XCD h exchange.
//
// Coherence: hbuf/flags only touched through agent-scope RELAXED atomics
// (global_load/store sc0 sc1 -> read/write-through at the LLC, the coherence
// point). Release ordering for flags comes from __syncthreads()'s
// s_waitcnt vmcnt(0) drain. No buffer_wbl2/buffer_inv anywhere.
//
// Flag layout: one flag per 64B cache line (FSTRIDE) so the spin-poll load
// traffic is spread across 64 LLC lines per group instead of hammering 4
// lines with 64K loads/µs (hot-bank serialization delayed both the flag
// stores and the detecting loads). Only wave 0 polls; other waves wait at a
// __syncthreads.
//
// Barrier scope: block (ng,cs) only exchanges h with blocks (ng,*) -> 4
// independent 64-block group barriers in-loop. The INIT wait is global
// (all 256 flags) because h0 is published grid-flat, i.e. by blocks of all
// groups. ng = (blk>>1)&3 places each group on one XCD pair under
// round-robin dispatch (heuristic only).
// ---------------------------------------------------------------------------
__global__ __launch_bounds__(256, 1)
void lstm_scan(const float* __restrict__ x,
               const float* __restrict__ h0,
               const __hip_bfloat16* __restrict__ WT,
               const float* __restrict__ bias,
               float* __restrict__ out,
               __hip_bfloat16* __restrict__ hbuf,   // 2 * 64*1024 bf16
               unsigned* __restrict__ flags) {      // 256 flags, 64B apart
    __shared__ __hip_bfloat16 Bt[16][BSTRIDE];  // [n][k]: k<1024 x, k>=1024 h
    __shared__ float lds_g[4][16][17];          // [gate][j_local][n_local]

    const int blk  = blockIdx.x;
    const int ng   = (blk >> 1) & 3;                    // XCD-pair group
    const int cs   = ((blk >> 3) << 1) | (blk & 1);     // 0..63 within group
    const int tid  = threadIdx.x;
    const int wave = tid >> 6;
    const int lane = tid & 63;
    const int n0 = ng * 16;
    const int j0 = cs * 16;
    unsigned* const gflag = flags + ng * 64 * FSTRIDE;  // this group's 64 lines

    const int frag_m = lane & 15;        // A: m (gate-col) / B: n (batch row)
    const int frag_k = (lane >> 4) * 8;  // k sub-offset within 32-chunk

    // ---- preload this wave's A fragments: 64 x short8 = 256 regs ----
    const __hip_bfloat16* wrow =
        WT + (size_t)(wave * HD + j0 + frag_m) * KTOT + frag_k;
    short8 wreg[64];
    #pragma unroll
    for (int i = 0; i < 32; ++i)
        wreg[i] = *(const short8*)(wrow + i * 32);
    #pragma unroll
    for (int i = 0; i < 32; ++i)
        wreg[32 + i] = *(const short8*)(wrow + DIM + i * 32);

    // ---- init: h0 -> hbuf[parity 0] (write-through, agent scope) ----
    const int flat = blk * 256 + tid;    // 0..65535, grid-flat coalesced
    __hip_atomic_store((unsigned short*)(hbuf + flat),
                       (unsigned short)__bfloat16_as_short(__float2bfloat16(h0[flat])),
                       __ATOMIC_RELAXED, __HIP_MEMORY_SCOPE_AGENT);

    __syncthreads();   // drains vmcnt for all waves -> h0 stores visible at LLC
    if (tid == 0)
        __hip_atomic_store(gflag + cs * FSTRIDE, 1u,
                           __ATOMIC_RELAXED, __HIP_MEMORY_SCOPE_AGENT);

    // ---- stage x_0 into Bt x-half (overlaps peers' init) ----
    {
        #pragma unroll
        for (int j = 0; j < 8; ++j) {
            const int c = j * 256 + tid;        // 16B chunk id, 0..2047
            const int r = c >> 7;               // row 0..15
            const int col = (c & 127) * 8;      // 0..1016
            const float* xs = x + (size_t)(n0 + r) * ROWSTRIDE + col;
            float4 f0 = *(const float4*)xs;
            float4 f1 = *(const float4*)(xs + 4);
            short8 v;
            v[0] = __bfloat16_as_short(__float2bfloat16(f0.x));
            v[1] = __bfloat16_as_short(__float2bfloat16(f0.y));
            v[2] = __bfloat16_as_short(__float2bfloat16(f0.z));
            v[3] = __bfloat16_as_short(__float2bfloat16(f0.w));
            v[4] = __bfloat16_as_short(__float2bfloat16(f1.x));
            v[5] = __bfloat16_as_short(__float2bfloat16(f1.y));
            v[6] = __bfloat16_as_short(__float2bfloat16(f1.z));
            v[7] = __bfloat16_as_short(__float2bfloat16(f1.w));
            *(short8*)&Bt[r][col] = v;
        }
    }

    // ---- GLOBAL init wait: h0 rows for this group were written by blocks
    //      of ALL groups (grid-flat publish) -> must see all 256 flags ----
    if (wave == 0) {
        for (;;) {
            unsigned a = __hip_atomic_load(flags + (lane       ) * FSTRIDE,
                                           __ATOMIC_RELAXED, __HIP_MEMORY_SCOPE_AGENT);
            unsigned b = __hip_atomic_load(flags + (64  + lane ) * FSTRIDE,
                                           __ATOMIC_RELAXED, __HIP_MEMORY_SCOPE_AGENT);
            unsigned c = __hip_atomic_load(flags + (128 + lane ) * FSTRIDE,
                                           __ATOMIC_RELAXED, __HIP_MEMORY_SCOPE_AGENT);
            unsigned d = __hip_atomic_load(flags + (192 + lane ) * FSTRIDE,
                                           __ATOMIC_RELAXED, __HIP_MEMORY_SCOPE_AGENT);
            int ok = (a >= 1u) && (b >= 1u) && (c >= 1u) && (d >= 1u);
            if (__all(ok)) break;
            __builtin_amdgcn_s_sleep(1);
        }
    }
    __syncthreads();   // release waves 1..3; also covers x_0 LDS writes

    // ---- epilogue mapping ----
    const int e_j = tid & 15;
    const int e_n = tid >> 4;
    float c_reg = 0.0f;
    const float bi  = bias[         j0 + e_j];
    const float bf_ = bias[1 * HD + j0 + e_j];
    const float bo  = bias[2 * HD + j0 + e_j];
    const float bg  = bias[3 * HD + j0 + e_j];
    float* out_e = out + (size_t)(n0 + e_n) * ROWSTRIDE + j0 + e_j;
    const int hb_idx = (n0 + e_n) * 1024 + j0 + e_j;
    const int q = lane >> 4;

    for (int t = 0; t < TS; ++t) {
        const int par = (t & 1) * 65536;

        // ---- stage h_{t-1} into Bt h-half (read-through 8B loads) ----
        #pragma unroll
        for (int j = 0; j < 8; ++j) {
            const int c = j * 256 + tid;
            const int r = c >> 7;
            const int col = (c & 127) * 8;
            const unsigned long long* hp =
                (const unsigned long long*)(hbuf + par + (n0 + r) * 1024 + col);
            unsigned long long lo = __hip_atomic_load(hp,
                __ATOMIC_RELAXED, __HIP_MEMORY_SCOPE_AGENT);
            unsigned long long hi = __hip_atomic_load(hp + 1,
                __ATOMIC_RELAXED, __HIP_MEMORY_SCOPE_AGENT);
            unsigned long long* dst = (unsigned long long*)&Bt[r][1024 + col];
            dst[0] = lo;
            dst[1] = hi;
        }
        __syncthreads();   // S1: x-half (prev tail) + h-half staged

        // ---- MFMA: A from regs, B from LDS. 4 independent acc chains
        //      (dep length 64 -> 16) so the matrix pipe runs issue-bound ----
        floatx4 a0 = {0.f, 0.f, 0.f, 0.f};
        floatx4 a1 = {0.f, 0.f, 0.f, 0.f};
        floatx4 a2 = {0.f, 0.f, 0.f, 0.f};
        floatx4 a3 = {0.f, 0.f, 0.f, 0.f};
        #pragma unroll
        for (int i = 0; i < 32; i += 2) {
            short8 b8a = *(const short8*)&Bt[frag_m][i * 32 + frag_k];
            short8 b8b = *(const short8*)&Bt[frag_m][(i + 1) * 32 + frag_k];
            a0 = __builtin_amdgcn_mfma_f32_16x16x32_bf16(wreg[i],     b8a, a0, 0, 0, 0);
            a1 = __builtin_amdgcn_mfma_f32_16x16x32_bf16(wreg[i + 1], b8b, a1, 0, 0, 0);
        }
        #pragma unroll
        for (int i = 0; i < 32; i += 2) {
            short8 b8a = *(const short8*)&Bt[frag_m][1024 + i * 32 + frag_k];
            short8 b8b = *(const short8*)&Bt[frag_m][1024 + (i + 1) * 32 + frag_k];
            a2 = __builtin_amdgcn_mfma_f32_16x16x32_bf16(wreg[32 + i], b8a, a2, 0, 0, 0);
            a3 = __builtin_amdgcn_mfma_f32_16x16x32_bf16(wreg[33 + i], b8b, a3, 0, 0, 0);
        }
        floatx4 acc = (a0 + a1) + (a2 + a3);

        // ---- gate tile -> lds_g ----
        #pragma unroll
        for (int r = 0; r < 4; ++r)
            lds_g[wave][q * 4 + r][frag_m] = acc[r];
        __syncthreads();   // S2

        // ---- gates + state update ----
        const float ai = lds_g[0][e_j][e_n] + bi;
        const float af = lds_g[1][e_j][e_n] + bf_;
        const float ao = lds_g[2][e_j][e_n] + bo;
        const float ag = lds_g[3][e_j][e_n] + bg;
        const float i_g = 1.0f / (1.0f + expf(-ai));
        const float f_g = 1.0f / (1.0f + expf(-af));
        const float o_g = 1.0f / (1.0f + expf(-ao));
        const float g_g = tanhf(ag);
        c_reg = f_g * c_reg + i_g * g_g;
        const float h = o_g * tanhf(c_reg);

        // ---- publish h (write-through), drain, signal ----
        const int npar = ((t + 1) & 1) * 65536;
        __hip_atomic_store((unsigned short*)(hbuf + npar + hb_idx),
                           (unsigned short)__bfloat16_as_short(__float2bfloat16(h)),
                           __ATOMIC_RELAXED, __HIP_MEMORY_SCOPE_AGENT);
        __syncthreads();   // S3: all waves' h stores LLC-acked
        if (tid == 0)
            __hip_atomic_store(gflag + cs * FSTRIDE, (unsigned)(t + 2),
                               __ATOMIC_RELAXED, __HIP_MEMORY_SCOPE_AGENT);

        if (t + 1 < TS) {
            // ---- stage x_{t+1} into Bt x-half (overlaps peers' arrival) ----
            #pragma unroll
            for (int j = 0; j < 8; ++j) {
                const int c = j * 256 + tid;
                const int r = c >> 7;
                const int col = (c & 127) * 8;
                const float* xs = x + (size_t)(n0 + r) * ROWSTRIDE
                                    + (size_t)(t + 1) * DIM + col;
                float4 f0 = *(const float4*)xs;
                float4 f1 = *(const float4*)(xs + 4);
                short8 v;
                v[0] = __bfloat16_as_short(__float2bfloat16(f0.x));
                v[1] = __bfloat16_as_short(__float2bfloat16(f0.y));
                v[2] = __bfloat16_as_short(__float2bfloat16(f0.z));
                v[3] = __bfloat16_as_short(__float2bfloat16(f0.w));
                v[4] = __bfloat16_as_short(__float2bfloat16(f1.x));
                v[5] = __bfloat16_as_short(__float2bfloat16(f1.y));
                v[6] = __bfloat16_as_short(__float2bfloat16(f1.z));
                v[7] = __bfloat16_as_short(__float2bfloat16(f1.w));
                *(short8*)&Bt[r][col] = v;
            }

            // fp32 output store — fire-and-forget, after x loads issued
            out_e[(size_t)t * HD] = h;

            // ---- group barrier: wave 0 polls 64 spread flag lines ----
            const unsigned tgt = (unsigned)(t + 2);
            if (wave == 0) {
                for (;;) {
                    unsigned v = __hip_atomic_load(gflag + lane * FSTRIDE,
                        __ATOMIC_RELAXED, __HIP_MEMORY_SCOPE_AGENT);
                    if (__all((int)(v >= tgt))) break;
                    __builtin_amdgcn_s_sleep(1);
                }
            }
            __syncthreads();   // S4: release all waves into next h-stage
        } else {
            out_e[(size_t)t * HD] = h;
        }
    }
}

// ---------------------------------------------------------------------------
extern "C" void kernel_launch(void* const* d_in, const int* in_sizes, int n_in,
                              void* d_out, int out_size, void* d_ws, size_t ws_size,
                              hipStream_t stream) {
    const float* x  = (const float*)d_in[0];
    const float* h0 = (const float*)d_in[1];
    const float* Wx = (const float*)d_in[2];
    const float* Wh = (const float*)d_in[3];
    const float* b  = (const float*)d_in[4];
    float* out = (float*)d_out;

    char* ws = (char*)d_ws;
    __hip_bfloat16* WT    = (__hip_bfloat16*)ws;                          // 16 MiB
    unsigned*       flags = (unsigned*)(ws + (16u << 20));                // 16 KiB (256 x 64B)
    __hip_bfloat16* hbuf  = (__hip_bfloat16*)(ws + (16u << 20) + 32768);  // 256 KiB

    hipMemsetAsync(flags, 0, 16384, stream);
    build_wt<<<dim3(128, 64), 256, 0, stream>>>(Wx, Wh, WT);
    lstm_scan<<<GRID_BLOCKS, 256, 0, stream>>>(x, h0, WT, b, out, hbuf, flags);
}

// Round 3
// 3282.451 us; speedup vs baseline: 3.3215x; 1.3658x over previous
//
#include <hip/hip_runtime.h>
#include <hip/hip_bf16.h>
#include <cmath>

typedef __attribute__((ext_vector_type(8))) short short8;   // 8 bf16 = 4 VGPRs
typedef __attribute__((ext_vector_type(4))) float floatx4;  // MFMA 16x16 accumulator

#define TS   512
#define DIM  1024
#define HD   1024
#define KTOT 2048
#define GRID_BLOCKS 256
#define XSTRIDE 1032                  // LDS row stride (bf16): 2064B = 516dw == 4 mod 32 (same as proven layout)
#define ROWSTRIDE ((size_t)TS * HD)   // batch-row stride of x and out (elements)

// ---------------------------------------------------------------------------
// One-time transpose + fp32->bf16: WT[j][k] = bf16( k<1024 ? Wx[k][j] : Wh[k-1024][j] )
// ---------------------------------------------------------------------------
__global__ void build_wt(const float* __restrict__ Wx,
                         const float* __restrict__ Wh,
                         __hip_bfloat16* __restrict__ WT) {
    __shared__ __hip_bfloat16 tile[32][33];
    const int j0 = blockIdx.x * 32;
    const int k0 = blockIdx.y * 32;
    const int tx = threadIdx.x & 31;
    const int ty = threadIdx.x >> 5;
    #pragma unroll
    for (int kk = 0; kk < 32; kk += 8) {
        const int k = k0 + ty + kk;
        const float* S = (k < DIM) ? (Wx + (size_t)k * 4096)
                                   : (Wh + (size_t)(k - DIM) * 4096);
        tile[ty + kk][tx] = __float2bfloat16(S[j0 + tx]);
    }
    __syncthreads();
    #pragma unroll
    for (int kk = 0; kk < 32; kk += 8) {
        const int j = j0 + ty + kk;
        WT[(size_t)j * KTOT + k0 + tx] = tile[tx][ty + kk];
    }
}

// ---------------------------------------------------------------------------
// Persistent LSTM scan — SELF-SYNCHRONIZING tagged h exchange. No flags, no
// grid/group barrier, no store-ack waits.
//
// hbuf32[parity][n*1024+j] = (bf16(h) << 16) | tag, tag = step+1 (h_t -> t+1).
// Producer: one relaxed agent-scope 4B store (write-through to LLC), fire &
// forget. Consumer: polls exactly the words it will consume until all carry
// the expected tag; the detecting load IS the data load (bf16 in the high
// half). This collapses the previous 4 serialized LLC round trips per step
// (h-ack, flag store, flag poll, h load) into ~1.
//
// Overwrite safety (no barriers needed): a word at parity p carries tags
// p+1, p+3, ... A producer can only write tag t+3 after its own iter-(t+2)
// poll saw tag t+3-1=t+2... i.e. after every block (incl. every reader of
// tag t+1) published end-of-iter t+1, which happens strictly after that
// reader consumed tag t+1. Monotone progress -> no deadlock.
//
// Stale-tag safety across dispatches: hbuf is memset to 0 every launch and
// tags start at 1.
// ---------------------------------------------------------------------------
__global__ __launch_bounds__(256, 1)
void lstm_scan(const float* __restrict__ x,
               const float* __restrict__ h0,
               const __hip_bfloat16* __restrict__ WT,
               const float* __restrict__ bias,
               float* __restrict__ out,
               unsigned* __restrict__ hbuf32) {   // 2 * 65536 tagged words
    __shared__ __hip_bfloat16 XB[2][16][XSTRIDE];  // x_t, double-buffered
    __shared__ __hip_bfloat16 Bh[16][XSTRIDE];     // h_{t-1}
    __shared__ float lds_g[4][16][17];             // [gate][j_local][n_local]

    const int blk  = blockIdx.x;
    const int ng   = (blk >> 1) & 3;                    // XCD-pair group
    const int cs   = ((blk >> 3) << 1) | (blk & 1);     // 0..63 within group
    const int tid  = threadIdx.x;
    const int wave = tid >> 6;
    const int lane = tid & 63;
    const int n0 = ng * 16;
    const int j0 = cs * 16;

    const int frag_m = lane & 15;        // A: m (gate-col) / B: n (batch row)
    const int frag_k = (lane >> 4) * 8;  // k sub-offset within 32-chunk

    // ---- publish h0 ASAP (tag 1, parity 0), grid-flat coalesced ----
    const int flat = blk * 256 + tid;    // 0..65535 == n*1024+j
    {
        const unsigned w0 =
            ((unsigned)(unsigned short)__bfloat16_as_short(__float2bfloat16(h0[flat])) << 16) | 1u;
        __hip_atomic_store(hbuf32 + flat, w0,
                           __ATOMIC_RELAXED, __HIP_MEMORY_SCOPE_AGENT);
    }

    // ---- preload this wave's A fragments: 64 x short8 ----
    const __hip_bfloat16* wrow =
        WT + (size_t)(wave * HD + j0 + frag_m) * KTOT + frag_k;
    short8 wreg[64];
    #pragma unroll
    for (int i = 0; i < 32; ++i)
        wreg[i] = *(const short8*)(wrow + i * 32);
    #pragma unroll
    for (int i = 0; i < 32; ++i)
        wreg[32 + i] = *(const short8*)(wrow + DIM + i * 32);

    // ---- stage x_0 -> XB[0] ----
    #pragma unroll
    for (int j = 0; j < 8; ++j) {
        const int c = j * 256 + tid;
        const int r = c >> 7;
        const int col = (c & 127) * 8;
        const float* xs = x + (size_t)(n0 + r) * ROWSTRIDE + col;
        float4 f0 = *(const float4*)xs;
        float4 f1 = *(const float4*)(xs + 4);
        short8 v;
        v[0] = __bfloat16_as_short(__float2bfloat16(f0.x));
        v[1] = __bfloat16_as_short(__float2bfloat16(f0.y));
        v[2] = __bfloat16_as_short(__float2bfloat16(f0.z));
        v[3] = __bfloat16_as_short(__float2bfloat16(f0.w));
        v[4] = __bfloat16_as_short(__float2bfloat16(f1.x));
        v[5] = __bfloat16_as_short(__float2bfloat16(f1.y));
        v[6] = __bfloat16_as_short(__float2bfloat16(f1.z));
        v[7] = __bfloat16_as_short(__float2bfloat16(f1.w));
        *(short8*)&XB[0][r][col] = v;
    }

    // ---- epilogue mapping ----
    const int e_j = tid & 15;
    const int e_n = tid >> 4;
    float c_reg = 0.0f;
    const float bi  = bias[         j0 + e_j];
    const float bf_ = bias[1 * HD + j0 + e_j];
    const float bo  = bias[2 * HD + j0 + e_j];
    const float bg  = bias[3 * HD + j0 + e_j];
    float* out_e = out + (size_t)(n0 + e_n) * ROWSTRIDE + j0 + e_j;
    const int hb_idx = (n0 + e_n) * 1024 + j0 + e_j;
    const int q = lane >> 4;

    for (int t = 0; t < TS; ++t) {
        const int par = t & 1;

        // ---- (A) issue x_{t+1} loads (cached); latency hides under poll ----
        float4 xf[16];
        if (t + 1 < TS) {
            #pragma unroll
            for (int j = 0; j < 8; ++j) {
                const int c = j * 256 + tid;
                const int r = c >> 7;
                const int col = (c & 127) * 8;
                const float* xs = x + (size_t)(n0 + r) * ROWSTRIDE
                                    + (size_t)(t + 1) * DIM + col;
                xf[2 * j]     = *(const float4*)xs;
                xf[2 * j + 1] = *(const float4*)(xs + 4);
            }
        }

        // ---- (B) poll tagged h_t words (the detecting load IS the data) ----
        unsigned long long hb[32];
        const unsigned long long* pb =
            (const unsigned long long*)hbuf32 + ((size_t)par << 15);
        const unsigned long long tagpat =
            (unsigned long long)(unsigned)(t + 1)
            | ((unsigned long long)(unsigned)(t + 1) << 32);
        bool ok;
        do {
            ok = true;
            #pragma unroll
            for (int j = 0; j < 8; ++j) {
                const int c = j * 256 + tid;
                const int r = c >> 7;
                const int col = (c & 127) * 8;
                const size_t o = (size_t)(((n0 + r) << 10) + col) >> 1;
                #pragma unroll
                for (int qq = 0; qq < 4; ++qq)
                    hb[4 * j + qq] = __hip_atomic_load(pb + o + qq,
                        __ATOMIC_RELAXED, __HIP_MEMORY_SCOPE_AGENT);
            }
            #pragma unroll
            for (int k = 0; k < 32; ++k)
                ok = ok && ((hb[k] & 0x0000FFFF0000FFFFull) == tagpat);
        } while (!__all((int)ok));

        // ---- (C) extract bf16 (high halves) -> Bh ----
        #pragma unroll
        for (int j = 0; j < 8; ++j) {
            const int c = j * 256 + tid;
            const int r = c >> 7;
            const int col = (c & 127) * 8;
            short8 v;
            #pragma unroll
            for (int qq = 0; qq < 4; ++qq) {
                const unsigned long long u = hb[4 * j + qq];
                v[2 * qq]     = (short)((unsigned)u >> 16);
                v[2 * qq + 1] = (short)(u >> 48);
            }
            *(short8*)&Bh[r][col] = v;
        }

        // ---- (D) convert & park x_{t+1} -> XB[(t+1)&1] ----
        if (t + 1 < TS) {
            #pragma unroll
            for (int j = 0; j < 8; ++j) {
                const int c = j * 256 + tid;
                const int r = c >> 7;
                const int col = (c & 127) * 8;
                const float4 f0 = xf[2 * j];
                const float4 f1 = xf[2 * j + 1];
                short8 v;
                v[0] = __bfloat16_as_short(__float2bfloat16(f0.x));
                v[1] = __bfloat16_as_short(__float2bfloat16(f0.y));
                v[2] = __bfloat16_as_short(__float2bfloat16(f0.z));
                v[3] = __bfloat16_as_short(__float2bfloat16(f0.w));
                v[4] = __bfloat16_as_short(__float2bfloat16(f1.x));
                v[5] = __bfloat16_as_short(__float2bfloat16(f1.y));
                v[6] = __bfloat16_as_short(__float2bfloat16(f1.z));
                v[7] = __bfloat16_as_short(__float2bfloat16(f1.w));
                *(short8*)&XB[(t + 1) & 1][r][col] = v;
            }
        }
        __syncthreads();   // S1: Bh + XB[(t+1)&1] staged; XB[par] stable

        // ---- MFMA: A from regs, B from LDS; 4 independent acc chains ----
        floatx4 a0 = {0.f, 0.f, 0.f, 0.f};
        floatx4 a1 = {0.f, 0.f, 0.f, 0.f};
        floatx4 a2 = {0.f, 0.f, 0.f, 0.f};
        floatx4 a3 = {0.f, 0.f, 0.f, 0.f};
        #pragma unroll
        for (int i = 0; i < 32; i += 2) {
            short8 b8a = *(const short8*)&XB[par][frag_m][i * 32 + frag_k];
            short8 b8b = *(const short8*)&XB[par][frag_m][(i + 1) * 32 + frag_k];
            a0 = __builtin_amdgcn_mfma_f32_16x16x32_bf16(wreg[i],     b8a, a0, 0, 0, 0);
            a1 = __builtin_amdgcn_mfma_f32_16x16x32_bf16(wreg[i + 1], b8b, a1, 0, 0, 0);
        }
        #pragma unroll
        for (int i = 0; i < 32; i += 2) {
            short8 b8a = *(const short8*)&Bh[frag_m][i * 32 + frag_k];
            short8 b8b = *(const short8*)&Bh[frag_m][(i + 1) * 32 + frag_k];
            a2 = __builtin_amdgcn_mfma_f32_16x16x32_bf16(wreg[32 + i], b8a, a2, 0, 0, 0);
            a3 = __builtin_amdgcn_mfma_f32_16x16x32_bf16(wreg[33 + i], b8b, a3, 0, 0, 0);
        }
        floatx4 acc = (a0 + a1) + (a2 + a3);

        // ---- gate tile -> lds_g ----
        #pragma unroll
        for (int r = 0; r < 4; ++r)
            lds_g[wave][q * 4 + r][frag_m] = acc[r];
        __syncthreads();   // S2

        // ---- gates + state update ----
        const float ai = lds_g[0][e_j][e_n] + bi;
        const float af = lds_g[1][e_j][e_n] + bf_;
        const float ao = lds_g[2][e_j][e_n] + bo;
        const float ag = lds_g[3][e_j][e_n] + bg;
        const float i_g = 1.0f / (1.0f + expf(-ai));
        const float f_g = 1.0f / (1.0f + expf(-af));
        const float o_g = 1.0f / (1.0f + expf(-ao));
        const float g_g = tanhf(ag);
        c_reg = f_g * c_reg + i_g * g_g;
        const float h = o_g * tanhf(c_reg);

        // ---- publish tagged h_{t+1}: ONE fire-and-forget store ----
        if (t + 1 < TS) {
            const unsigned wrd =
                ((unsigned)(unsigned short)__bfloat16_as_short(__float2bfloat16(h)) << 16)
                | (unsigned)(t + 2);
            __hip_atomic_store(hbuf32 + (((size_t)((t + 1) & 1)) << 16) + hb_idx, wrd,
                               __ATOMIC_RELAXED, __HIP_MEMORY_SCOPE_AGENT);
        }

        // fp32 output — fire-and-forget
        out_e[(size_t)t * HD] = h;
    }
}

// ---------------------------------------------------------------------------
extern "C" void kernel_launch(void* const* d_in, const int* in_sizes, int n_in,
                              void* d_out, int out_size, void* d_ws, size_t ws_size,
                              hipStream_t stream) {
    const float* x  = (const float*)d_in[0];
    const float* h0 = (const float*)d_in[1];
    const float* Wx = (const float*)d_in[2];
    const float* Wh = (const float*)d_in[3];
    const float* b  = (const float*)d_in[4];
    float* out = (float*)d_out;

    char* ws = (char*)d_ws;
    __hip_bfloat16* WT     = (__hip_bfloat16*)ws;              // 16 MiB
    unsigned*       hbuf32 = (unsigned*)(ws + (16u << 20));    // 512 KiB (2 x 65536 x 4B)

    hipMemsetAsync(hbuf32, 0, 2 * 65536 * sizeof(unsigned), stream);  // kill stale tags
    build_wt<<<dim3(128, 64), 256, 0, stream>>>(Wx, Wh, WT);
    lstm_scan<<<GRID_BLOCKS, 256, 0, stream>>>(x, h0, WT, b, out, hbuf32);
}